// Round 1
// baseline (15804.285 us; speedup 1.0000x reference)
//
#include <hip/hip_runtime.h>

// BiLSTM(2 layers, bidir, H=512, E=1024) + FC(24) + CRF llh on MI355X.
// Strategy:
//  - hoist x@Wih^T out of the recurrence (big bf16 MFMA GEMMs, fp32 Gin)
//  - persistent spin-synced recurrence kernel: 64 WGs/dir, Whh slice in LDS,
//    c-state in regs, h exchanged via global + device-scope flags
//  - skinny MFMA FC, per-batch-element CRF DP with shfl-based logsumexp

typedef __bf16 bf16;
typedef __bf16 bf16x8 __attribute__((ext_vector_type(8)));
typedef __bf16 bf16x4 __attribute__((ext_vector_type(4)));
typedef float f32x4 __attribute__((ext_vector_type(4)));
typedef unsigned int u32;

#define TT 512
#define BB 32
#define HH 512
#define CC_ 24
#define MROWS 16384   // T*B
#define KDIM 1024     // E == 2H
#define NGATE 2048    // 4H

__device__ __forceinline__ f32x4 mfma16(bf16x8 a, bf16x8 b, f32x4 c) {
  return __builtin_amdgcn_mfma_f32_16x16x32_bf16(a, b, c, 0, 0, 0);
}
__device__ __forceinline__ float sigmoidf_(float x) { return 1.f / (1.f + __expf(-x)); }

// ---------------- weight conversion fp32 -> bf16 ----------------
__global__ __launch_bounds__(256) void convert_w_k(
    const float* __restrict__ wih, const float* __restrict__ whh, const float* __restrict__ fcw,
    bf16* __restrict__ wihb, bf16* __restrict__ whhb, bf16* __restrict__ fcwb) {
  const int n1 = (2 * 2 * NGATE * KDIM) / 4;   // wih chunks of 4
  const int n2 = (2 * 2 * NGATE * HH) / 4;     // whh
  const int n3 = (32 * KDIM) / 4;              // fcw padded to 32 rows
  int stride = gridDim.x * blockDim.x;
  for (int i = blockIdx.x * blockDim.x + threadIdx.x; i < n1 + n2 + n3; i += stride) {
    float4 v;
    bf16* dst;
    if (i < n1) {
      v = ((const float4*)wih)[i];
      dst = wihb + (size_t)i * 4;
    } else if (i < n1 + n2) {
      int j = i - n1;
      v = ((const float4*)whh)[j];
      dst = whhb + (size_t)j * 4;
    } else {
      int j = i - n1 - n2;
      if ((j >> 8) < CC_) v = ((const float4*)fcw)[j];     // row = (j*4)>>10 = j>>8
      else                v = make_float4(0.f, 0.f, 0.f, 0.f);
      dst = fcwb + (size_t)j * 4;
    }
    bf16x4 o; o[0] = (bf16)v.x; o[1] = (bf16)v.y; o[2] = (bf16)v.z; o[3] = (bf16)v.w;
    *(bf16x4*)dst = o;
  }
}

// ---------------- embedding gather -> xt[t*32+b][1024] bf16 ----------------
__global__ __launch_bounds__(64) void embed_k(const int* __restrict__ x,
                                              const float* __restrict__ emb,
                                              bf16* __restrict__ xt) {
  int row = blockIdx.x;            // t*32 + b
  int t = row >> 5, b = row & 31;
  int tok = x[b * TT + t];
  const float4* src = (const float4*)(emb + (size_t)tok * KDIM);
  bf16* dst = xt + (size_t)row * KDIM;
  int i = threadIdx.x;
#pragma unroll
  for (int c = 0; c < 4; ++c) {
    float4 v = src[i + 64 * c];
    bf16x4 o; o[0] = (bf16)v.x; o[1] = (bf16)v.y; o[2] = (bf16)v.z; o[3] = (bf16)v.w;
    *(bf16x4*)(dst + (size_t)(i + 64 * c) * 4) = o;
  }
}

// ---------------- input GEMM: Gin[dir][row][n] = A@W^T + bih + bhh (fp32 out) ----------------
// A [16384][1024] bf16, W [2][2048][1024] bf16 (row n = gate output, B^T form).
// 128x128 tile, BK=64, 256 thr (4 waves 2x2), each wave 4x4 tiles of 16x16x32.
__global__ __launch_bounds__(256, 2) void gemm_in_k(
    const bf16* __restrict__ A, const bf16* __restrict__ W,
    const float* __restrict__ bih, const float* __restrict__ bhh,
    float* __restrict__ Gin) {
  __shared__ bf16 As[128 * 72];   // 64 cols + 8 pad
  __shared__ bf16 Ws[128 * 72];
  int dir = blockIdx.z;
  const bf16* Wd = W + (size_t)dir * NGATE * KDIM;
  const float* bi = bih + dir * NGATE;
  const float* bh = bhh + dir * NGATE;
  float* G = Gin + (size_t)dir * MROWS * NGATE;
  int m0 = blockIdx.y * 128;
  int n0 = blockIdx.x * 128;
  int tid = threadIdx.x;
  int lane = tid & 63, wave = tid >> 6;
  int wm = wave >> 1, wn = wave & 1;
  int cn = lane & 15, quad = lane >> 4;

  f32x4 zz = {0.f, 0.f, 0.f, 0.f};
  f32x4 acc[4][4];
#pragma unroll
  for (int a = 0; a < 4; ++a)
#pragma unroll
    for (int b = 0; b < 4; ++b) acc[a][b] = zz;

  for (int k0 = 0; k0 < KDIM; k0 += 64) {
    __syncthreads();
#pragma unroll
    for (int j = 0; j < 4; ++j) {
      int cch = tid + 256 * j;          // 0..1023
      int row = cch >> 3, kq = cch & 7;
      *(bf16x8*)&As[row * 72 + kq * 8] =
          *(const bf16x8*)&A[(size_t)(m0 + row) * KDIM + k0 + kq * 8];
      *(bf16x8*)&Ws[row * 72 + kq * 8] =
          *(const bf16x8*)&Wd[(size_t)(n0 + row) * KDIM + k0 + kq * 8];
    }
    __syncthreads();
#pragma unroll
    for (int kc = 0; kc < 2; ++kc) {
      bf16x8 af[4], bw[4];
#pragma unroll
      for (int mt = 0; mt < 4; ++mt)
        af[mt] = *(const bf16x8*)&As[(wm * 64 + mt * 16 + cn) * 72 + kc * 32 + quad * 8];
#pragma unroll
      for (int nt = 0; nt < 4; ++nt)
        bw[nt] = *(const bf16x8*)&Ws[(wn * 64 + nt * 16 + cn) * 72 + kc * 32 + quad * 8];
#pragma unroll
      for (int mt = 0; mt < 4; ++mt)
#pragma unroll
        for (int nt = 0; nt < 4; ++nt)
          acc[mt][nt] = mfma16(af[mt], bw[nt], acc[mt][nt]);
    }
  }
#pragma unroll
  for (int nt = 0; nt < 4; ++nt) {
    int n = n0 + wn * 64 + nt * 16 + cn;
    float bias = bi[n] + bh[n];
#pragma unroll
    for (int mt = 0; mt < 4; ++mt) {
#pragma unroll
      for (int r = 0; r < 4; ++r) {
        int row = m0 + wm * 64 + mt * 16 + quad * 4 + r;
        G[(size_t)row * NGATE + n] = acc[mt][nt][r] + bias;
      }
    }
  }
}

// ---------------- persistent recurrence ----------------
// grid (64, 2): 64 WGs per direction, 1 wave each. WG owns 8 h-columns (j0=wg*8).
// LDS holds its Whh slice as B-fragments: tile0 cols = [i(8)|f(8)], tile1 = [g(8)|o(8)].
__global__ __launch_bounds__(64) void rec_k(
    const float* __restrict__ Gin,   // [2][16384][2048] fp32 (pre-activations + bias)
    const bf16* __restrict__ Whh,    // [2][2048][512] this layer's, bf16
    bf16* __restrict__ hbuf,         // [16384][1024]: fwd cols 0-511, bwd 512-1023
    u32* __restrict__ flags) {       // [2][512][64], pre-zeroed
  int wg = blockIdx.x;
  int dir = blockIdx.y;
  int lane = threadIdx.x;
  int cn = lane & 15, quad = lane >> 4;
  int j0 = wg * 8;
  const bf16* Wd = Whh + (size_t)dir * NGATE * HH;
  const float* G = Gin + (size_t)dir * MROWS * NGATE;
  u32* fl = flags + (size_t)dir * TT * 64;

  __shared__ bf16 Bl[2 * 16 * 520];   // [tile][col16][512+8 pad]
  for (int c = lane; c < 2 * 16 * 64; c += 64) {
    int col = c >> 6;                 // 0..31 = nt*16+ccn
    int kc8 = c & 63;                 // k chunk of 8
    int nt = col >> 4, ccn = col & 15;
    int gate = nt * 2 + (ccn >> 3);
    int jj_ = ccn & 7;
    int n = gate * HH + j0 + jj_;
    *(bf16x8*)&Bl[col * 520 + kc8 * 8] = *(const bf16x8*)&Wd[(size_t)n * HH + kc8 * 8];
  }
  __syncthreads();

  float cst[2][4];
#pragma unroll
  for (int mt = 0; mt < 2; ++mt)
#pragma unroll
    for (int r = 0; r < 4; ++r) cst[mt][r] = 0.f;
  bool active = cn < 8;
  int jj = cn & 7;
  f32x4 zz = {0.f, 0.f, 0.f, 0.f};

  for (int s = 0; s < TT; ++s) {
    int t = dir ? (TT - 1 - s) : s;
    f32x4 acc[2][2];
    acc[0][0] = zz; acc[0][1] = zz; acc[1][0] = zz; acc[1][1] = zz;
    if (s > 0) {
      int tp = dir ? (t + 1) : (t - 1);
      u32* f = fl + (size_t)(s - 1) * 64;
      while (__hip_atomic_load(&f[lane], __ATOMIC_RELAXED, __HIP_MEMORY_SCOPE_AGENT) == 0u)
        __builtin_amdgcn_s_sleep(2);
      __threadfence();   // acquire: make other WGs' h stores visible (cross-XCD)
      const bf16* hb = hbuf + (size_t)(tp * BB) * KDIM + dir * HH;
#pragma unroll 4
      for (int k0 = 0; k0 < HH; k0 += 32) {
        bf16x8 a0 = *(const bf16x8*)&hb[(size_t)cn * KDIM + k0 + quad * 8];
        bf16x8 a1 = *(const bf16x8*)&hb[(size_t)(cn + 16) * KDIM + k0 + quad * 8];
        bf16x8 b0 = *(const bf16x8*)&Bl[(0 * 16 + cn) * 520 + k0 + quad * 8];
        bf16x8 b1 = *(const bf16x8*)&Bl[(1 * 16 + cn) * 520 + k0 + quad * 8];
        acc[0][0] = mfma16(a0, b0, acc[0][0]);
        acc[0][1] = mfma16(a0, b1, acc[0][1]);
        acc[1][0] = mfma16(a1, b0, acc[1][0]);
        acc[1][1] = mfma16(a1, b1, acc[1][1]);
      }
    }
#pragma unroll
    for (int mt = 0; mt < 2; ++mt) {
#pragma unroll
      for (int r = 0; r < 4; ++r) {
        float ip = acc[mt][0][r], gp = acc[mt][1][r];
        float fp = __shfl(ip, lane + 8);   // f gate lives 8 lanes over
        float op = __shfl(gp, lane + 8);   // o gate lives 8 lanes over
        if (active) {
          int b = mt * 16 + quad * 4 + r;
          const float* g = G + (size_t)(t * BB + b) * NGATE + j0 + jj;
          float xi = ip + g[0];
          float xf = fp + g[512];
          float xg = gp + g[1024];
          float xo = op + g[1536];
          float it = sigmoidf_(xi);
          float ft = sigmoidf_(xf);
          float gt = tanhf(xg);
          float ot = sigmoidf_(xo);
          float cc = ft * cst[mt][r] + it * gt;
          cst[mt][r] = cc;
          float hh = ot * tanhf(cc);
          hbuf[(size_t)(t * BB + b) * KDIM + dir * HH + j0 + jj] = (bf16)hh;
        }
      }
    }
    __threadfence();   // release: flush h stores (cross-XCD L2 writeback)
    if (lane == 0)
      __hip_atomic_store(&fl[(size_t)s * 64 + wg], 1u, __ATOMIC_RELAXED,
                         __HIP_MEMORY_SCOPE_AGENT);
  }
}

// ---------------- FC: logits[b][t][c] = h1 @ fcw^T + fcb ----------------
__global__ __launch_bounds__(64) void gemm_fc_k(
    const bf16* __restrict__ hbuf,   // [16384][1024]
    const bf16* __restrict__ fcw,    // [32][1024] (rows 24..31 zero)
    const float* __restrict__ fcb,   // [24]
    float* __restrict__ outp) {      // [32][512][24] + scalar slot
  int m0 = blockIdx.x * 16;
  int lane = threadIdx.x;
  int cn = lane & 15, quad = lane >> 4;
  f32x4 acc0 = {0.f, 0.f, 0.f, 0.f}, acc1 = {0.f, 0.f, 0.f, 0.f};
  for (int k0 = 0; k0 < KDIM; k0 += 32) {
    bf16x8 a  = *(const bf16x8*)&hbuf[(size_t)(m0 + cn) * KDIM + k0 + quad * 8];
    bf16x8 b0 = *(const bf16x8*)&fcw[(size_t)cn * KDIM + k0 + quad * 8];
    bf16x8 b1 = *(const bf16x8*)&fcw[(size_t)(cn + 16) * KDIM + k0 + quad * 8];
    acc0 = mfma16(a, b0, acc0);
    acc1 = mfma16(a, b1, acc1);
  }
#pragma unroll
  for (int r = 0; r < 4; ++r) {
    int row = m0 + quad * 4 + r;
    int t = row >> 5, b = row & 31;
    float* o = outp + (size_t)b * (TT * CC_) + (size_t)t * CC_;
    o[cn] = acc0[r] + fcb[cn];
    int c1 = cn + 16;
    if (c1 < CC_) o[c1] = acc1[r] + fcb[c1];
  }
  if (blockIdx.x == 0 && lane == 0) outp[(size_t)BB * TT * CC_] = 0.f;  // zero llh slot
}

// ---------------- CRF: one WG per batch element ----------------
__global__ __launch_bounds__(64) void crf_k(
    const float* __restrict__ em,     // d_out logits [32][512][24]
    const int* __restrict__ labels,   // [32][512]
    const float* __restrict__ start_, const float* __restrict__ end_,
    const float* __restrict__ trans, float* __restrict__ result) {
  int b = blockIdx.x;
  int j = threadIdx.x;
  bool act = j < CC_;
  int jc = act ? j : 0;
  float tcol[CC_];
#pragma unroll
  for (int i = 0; i < CC_; ++i) tcol[i] = trans[i * CC_ + jc];
  const float* emb_ = em + (size_t)b * (TT * CC_);
  float alpha = act ? (start_[jc] + emb_[jc]) : -1e30f;
  for (int t = 1; t < TT; ++t) {
    float m = -1e30f;
#pragma unroll
    for (int i = 0; i < CC_; ++i) {
      float ai = __shfl(alpha, i);
      m = fmaxf(m, ai + tcol[i]);
    }
    float ssum = 0.f;
#pragma unroll
    for (int i = 0; i < CC_; ++i) {
      float ai = __shfl(alpha, i);
      ssum += __expf(ai + tcol[i] - m);
    }
    float na = m + __logf(ssum) + emb_[(size_t)t * CC_ + jc];
    alpha = act ? na : -1e30f;
  }
  float v = act ? (alpha + end_[jc]) : -1e30f;
  float mm = v;
#pragma unroll
  for (int off = 32; off; off >>= 1) mm = fmaxf(mm, __shfl_xor(mm, off));
  float e = act ? __expf(v - mm) : 0.f;
#pragma unroll
  for (int off = 32; off; off >>= 1) e += __shfl_xor(e, off);
  float logZ = mm + __logf(e);
  // gold-path numerator
  float part = 0.f;
  for (int t = j; t < TT; t += 64) {
    int tag = labels[b * TT + t];
    part += emb_[(size_t)t * CC_ + tag];
    if (t < TT - 1) part += trans[tag * CC_ + labels[b * TT + t + 1]];
  }
#pragma unroll
  for (int off = 32; off; off >>= 1) part += __shfl_xor(part, off);
  if (j == 0) {
    float num = part + start_[labels[b * TT]] + end_[labels[b * TT + TT - 1]];
    atomicAdd(result, logZ - num);   // accumulates -llh
  }
}

extern "C" void kernel_launch(void* const* d_in, const int* in_sizes, int n_in,
                              void* d_out, int out_size, void* d_ws, size_t ws_size,
                              hipStream_t stream) {
  const int*   x      = (const int*)d_in[0];
  const int*   labels = (const int*)d_in[1];
  const float* emb    = (const float*)d_in[2];
  const float* w_ih   = (const float*)d_in[3];
  const float* w_hh   = (const float*)d_in[4];
  const float* b_ih   = (const float*)d_in[5];
  const float* b_hh   = (const float*)d_in[6];
  const float* fc_w   = (const float*)d_in[7];
  const float* fc_b   = (const float*)d_in[8];
  const float* crf_s  = (const float*)d_in[9];
  const float* crf_e  = (const float*)d_in[10];
  const float* crf_t  = (const float*)d_in[11];
  float* out = (float*)d_out;
  (void)in_sizes; (void)n_in; (void)out_size; (void)ws_size;

  // workspace carve-up (~395 MB total)
  char* ws = (char*)d_ws;
  bf16* xt    = (bf16*)ws;                         // 33,554,432 B
  bf16* h0    = (bf16*)(ws + 33554432);            // 33,554,432
  bf16* h1    = (bf16*)(ws + 67108864);            // 33,554,432
  bf16* wihb  = (bf16*)(ws + 100663296);           // 16,777,216
  bf16* whhb  = (bf16*)(ws + 117440512);           //  8,388,608
  bf16* fcwb  = (bf16*)(ws + 125829120);           //     65,536
  float* gin  = (float*)(ws + 125894656);          // 268,435,456
  u32* flags  = (u32*)(ws + 394330112);            //    524,288

  hipMemsetAsync(flags, 0, 2 * 2 * TT * 64 * sizeof(u32), stream);
  convert_w_k<<<2048, 256, 0, stream>>>(w_ih, w_hh, fc_w, wihb, whhb, fcwb);
  embed_k<<<MROWS, 64, 0, stream>>>(x, emb, xt);

  // layer 0
  gemm_in_k<<<dim3(16, 128, 2), 256, 0, stream>>>(xt, wihb, b_ih, b_hh, gin);
  rec_k<<<dim3(64, 2), 64, 0, stream>>>(gin, whhb, h0, flags);
  // layer 1
  gemm_in_k<<<dim3(16, 128, 2), 256, 0, stream>>>(
      h0, wihb + (size_t)2 * NGATE * KDIM, b_ih + 2 * NGATE, b_hh + 2 * NGATE, gin);
  rec_k<<<dim3(64, 2), 64, 0, stream>>>(
      gin, whhb + (size_t)2 * NGATE * HH, h1, flags + 2 * TT * 64);

  gemm_fc_k<<<MROWS / 16, 64, 0, stream>>>(h1, fcwb, fc_b, out);
  crf_k<<<BB, 64, 0, stream>>>(out, labels, crf_s, crf_e, crf_t,
                               out + (size_t)BB * TT * CC_);
}

// Round 2
// 9724.591 us; speedup vs baseline: 1.6252x; 1.6252x over previous
//
#include <hip/hip_runtime.h>

// BiLSTM(2 layers, bidir, H=512, E=1024) + FC(24) + CRF llh on MI355X.
// R2: rec_k sync rebuilt — no __threadfence (was full L2 inv+wb per step).
//  - h exchanged via relaxed AGENT-scope 8B atomics in a swizzled buffer hx
//    matching the MFMA A-frag layout exactly (1 store/lane, contiguous loads)
//  - release = s_waitcnt vmcnt(0) + relaxed flag; acquire = spin + vmcnt(0)
//  - Gin in fp16, per-WG-contiguous [dir][wg][row][jj*4+gate], prefetched
//    into registers BEFORE the spin wait (latency hidden behind sync)

typedef __bf16 bf16;
typedef _Float16 f16;
typedef __bf16 bf16x8 __attribute__((ext_vector_type(8)));
typedef __bf16 bf16x4 __attribute__((ext_vector_type(4)));
typedef _Float16 f16x4 __attribute__((ext_vector_type(4)));
typedef float f32x4 __attribute__((ext_vector_type(4)));
typedef unsigned int u32;
typedef unsigned long long u64;

#define TT 512
#define BB 32
#define HH 512
#define CC_ 24
#define MROWS 16384   // T*B
#define KDIM 1024     // E == 2H
#define NGATE 2048    // 4H

__device__ __forceinline__ f32x4 mfma16(bf16x8 a, bf16x8 b, f32x4 c) {
  return __builtin_amdgcn_mfma_f32_16x16x32_bf16(a, b, c, 0, 0, 0);
}
__device__ __forceinline__ float sigmoidf_(float x) { return 1.f / (1.f + __expf(-x)); }
__device__ __forceinline__ float tanhf_(float x) {
  float e = __expf(2.f * x);           // inf-safe: x>>0 -> 1-0=1, x<<0 -> 1-2=-1
  return 1.f - 2.f / (e + 1.f);
}

// ---------------- weight conversion fp32 -> bf16 ----------------
__global__ __launch_bounds__(256) void convert_w_k(
    const float* __restrict__ wih, const float* __restrict__ whh, const float* __restrict__ fcw,
    bf16* __restrict__ wihb, bf16* __restrict__ whhb, bf16* __restrict__ fcwb) {
  const int n1 = (2 * 2 * NGATE * KDIM) / 4;
  const int n2 = (2 * 2 * NGATE * HH) / 4;
  const int n3 = (32 * KDIM) / 4;
  int stride = gridDim.x * blockDim.x;
  for (int i = blockIdx.x * blockDim.x + threadIdx.x; i < n1 + n2 + n3; i += stride) {
    float4 v;
    bf16* dst;
    if (i < n1) {
      v = ((const float4*)wih)[i];
      dst = wihb + (size_t)i * 4;
    } else if (i < n1 + n2) {
      int j = i - n1;
      v = ((const float4*)whh)[j];
      dst = whhb + (size_t)j * 4;
    } else {
      int j = i - n1 - n2;
      if ((j >> 8) < CC_) v = ((const float4*)fcw)[j];
      else                v = make_float4(0.f, 0.f, 0.f, 0.f);
      dst = fcwb + (size_t)j * 4;
    }
    bf16x4 o; o[0] = (bf16)v.x; o[1] = (bf16)v.y; o[2] = (bf16)v.z; o[3] = (bf16)v.w;
    *(bf16x4*)dst = o;
  }
}

// ---------------- embedding gather -> xt[t*32+b][1024] bf16 ----------------
__global__ __launch_bounds__(64) void embed_k(const int* __restrict__ x,
                                              const float* __restrict__ emb,
                                              bf16* __restrict__ xt) {
  int row = blockIdx.x;
  int t = row >> 5, b = row & 31;
  int tok = x[b * TT + t];
  const float4* src = (const float4*)(emb + (size_t)tok * KDIM);
  bf16* dst = xt + (size_t)row * KDIM;
  int i = threadIdx.x;
#pragma unroll
  for (int c = 0; c < 4; ++c) {
    float4 v = src[i + 64 * c];
    bf16x4 o; o[0] = (bf16)v.x; o[1] = (bf16)v.y; o[2] = (bf16)v.z; o[3] = (bf16)v.w;
    *(bf16x4*)(dst + (size_t)(i + 64 * c) * 4) = o;
  }
}

// ---------------- input GEMM -> Gin fp16, per-WG layout ----------------
// Gh[dir][wg(64)][row(16384)][jj(8)*4+gate(4)]  (each WG's data contiguous)
__global__ __launch_bounds__(256, 2) void gemm_in_k(
    const bf16* __restrict__ A, const bf16* __restrict__ W,
    const float* __restrict__ bih, const float* __restrict__ bhh,
    f16* __restrict__ Gh) {
  __shared__ bf16 As[128 * 72];
  __shared__ bf16 Ws[128 * 72];
  int dir = blockIdx.z;
  const bf16* Wd = W + (size_t)dir * NGATE * KDIM;
  const float* bi = bih + dir * NGATE;
  const float* bh = bhh + dir * NGATE;
  f16* G = Gh + (size_t)dir * 64 * MROWS * 32;
  int m0 = blockIdx.y * 128;
  int n0 = blockIdx.x * 128;
  int tid = threadIdx.x;
  int lane = tid & 63, wave = tid >> 6;
  int wm = wave >> 1, wn = wave & 1;
  int cn = lane & 15, quad = lane >> 4;

  f32x4 zz = {0.f, 0.f, 0.f, 0.f};
  f32x4 acc[4][4];
#pragma unroll
  for (int a = 0; a < 4; ++a)
#pragma unroll
    for (int b = 0; b < 4; ++b) acc[a][b] = zz;

  for (int k0 = 0; k0 < KDIM; k0 += 64) {
    __syncthreads();
#pragma unroll
    for (int j = 0; j < 4; ++j) {
      int cch = tid + 256 * j;
      int row = cch >> 3, kq = cch & 7;
      *(bf16x8*)&As[row * 72 + kq * 8] =
          *(const bf16x8*)&A[(size_t)(m0 + row) * KDIM + k0 + kq * 8];
      *(bf16x8*)&Ws[row * 72 + kq * 8] =
          *(const bf16x8*)&Wd[(size_t)(n0 + row) * KDIM + k0 + kq * 8];
    }
    __syncthreads();
#pragma unroll
    for (int kc = 0; kc < 2; ++kc) {
      bf16x8 af[4], bw[4];
#pragma unroll
      for (int mt = 0; mt < 4; ++mt)
        af[mt] = *(const bf16x8*)&As[(wm * 64 + mt * 16 + cn) * 72 + kc * 32 + quad * 8];
#pragma unroll
      for (int nt = 0; nt < 4; ++nt)
        bw[nt] = *(const bf16x8*)&Ws[(wn * 64 + nt * 16 + cn) * 72 + kc * 32 + quad * 8];
#pragma unroll
      for (int mt = 0; mt < 4; ++mt)
#pragma unroll
        for (int nt = 0; nt < 4; ++nt)
          acc[mt][nt] = mfma16(af[mt], bw[nt], acc[mt][nt]);
    }
  }
#pragma unroll
  for (int nt = 0; nt < 4; ++nt) {
    int n = n0 + wn * 64 + nt * 16 + cn;
    float bias = bi[n] + bh[n];
    int col = n & 511, gate = n >> 9;
    size_t base = (size_t)(col >> 3) * MROWS * 32 + (size_t)(col & 7) * 4 + gate;
#pragma unroll
    for (int mt = 0; mt < 4; ++mt) {
#pragma unroll
      for (int r = 0; r < 4; ++r) {
        int row = m0 + wm * 64 + mt * 16 + quad * 4 + r;
        G[base + (size_t)row * 32] = (f16)(acc[mt][nt][r] + bias);
      }
    }
  }
}

// ---------------- persistent recurrence (fence-free coherent exchange) ----
// grid (64, 2): 64 WGs/dir, 1 wave each; WG owns 8 h-cols (j0=wg*8).
// hx[dir][t] is a 32KB block in A-frag order: [kk(16)][piece(4)][lane(64)] x 8B
//   piece = (row>=16)*2 + half;  slot lane = (row&15) + k_quad*16.
__global__ __launch_bounds__(64) void rec_k(
    const f16* __restrict__ Gin,     // [2][64][16384][32] fp16
    const bf16* __restrict__ Whh,    // [2][2048][512] bf16
    bf16* __restrict__ hbuf,         // [16384][1024] cached out (next layer)
    u64* __restrict__ hx,            // [2][512][4096] 8B slots, coherent
    u32* __restrict__ flags) {       // [2][512][64], pre-zeroed
  int wg = blockIdx.x;
  int dir = blockIdx.y;
  int lane = threadIdx.x;
  int cn = lane & 15, quad = lane >> 4;
  int j0 = wg * 8;
  const bf16* Wd = Whh + (size_t)dir * NGATE * HH;
  const f16* Gw = Gin + ((size_t)dir * 64 + wg) * MROWS * 32;
  u64* hxd = hx + (size_t)dir * TT * 4096;
  u32* fl = flags + (size_t)dir * TT * 64;

  __shared__ bf16 Bl[2 * 16 * 520];   // Whh slice as B-frags
  __shared__ bf16 hS[32][8];          // transpose staging for h output
  for (int c = lane; c < 2 * 16 * 64; c += 64) {
    int col = c >> 6;
    int kc8 = c & 63;
    int nt = col >> 4, ccn = col & 15;
    int gate = nt * 2 + (ccn >> 3);
    int jj_ = ccn & 7;
    int n = gate * HH + j0 + jj_;
    *(bf16x8*)&Bl[col * 520 + kc8 * 8] = *(const bf16x8*)&Wd[(size_t)n * HH + kc8 * 8];
  }
  __syncthreads();

  float cst[2][4];
#pragma unroll
  for (int mt = 0; mt < 2; ++mt)
#pragma unroll
    for (int r = 0; r < 4; ++r) cst[mt][r] = 0.f;
  bool active = cn < 8;
  int jj = cn & 7;
  f32x4 zz = {0.f, 0.f, 0.f, 0.f};

  // per-lane pack/store geometry (constant across steps)
  int pb = lane >> 1, half = lane & 1;                 // this lane packs row pb, cols half*4..+3
  int sIdx = (j0 >> 5) * 256 + (((pb >= 16) ? 2 : 0) + half) * 64 +
             ((j0 >> 3) & 3) * 16 + (pb & 15);         // 8B slot within hx[t]
  size_t hbOff = ((size_t)pb * KDIM + dir * HH + j0 + half * 4);  // within row t*BB

  for (int s = 0; s < TT; ++s) {
    int t = dir ? (TT - 1 - s) : s;
    // prefetch this step's gate pre-activations (overlaps the spin wait)
    f16x4 gp_[2][4];
    if (active) {
#pragma unroll
      for (int mt = 0; mt < 2; ++mt)
#pragma unroll
        for (int r = 0; r < 4; ++r) {
          int b = mt * 16 + quad * 4 + r;
          gp_[mt][r] = *(const f16x4*)&Gw[(size_t)(t * BB + b) * 32 + jj * 4];
        }
    }
    f32x4 acc[2][2];
    acc[0][0] = zz; acc[0][1] = zz; acc[1][0] = zz; acc[1][1] = zz;
    if (s > 0) {
      int tp = dir ? (t + 1) : (t - 1);
      u32* f = fl + (size_t)(s - 1) * 64;
      while (__hip_atomic_load(&f[lane], __ATOMIC_RELAXED, __HIP_MEMORY_SCOPE_AGENT) == 0u)
        __builtin_amdgcn_s_sleep(1);
      asm volatile("s_waitcnt vmcnt(0)" ::: "memory");  // acquire (loads below stay below)
      const u64* hb8 = hxd + (size_t)tp * 4096;
#pragma unroll 4
      for (int kk = 0; kk < 16; ++kk) {
        union { u64 u[2]; bf16x8 v; } a0, a1;
        a0.u[0] = __hip_atomic_load(&hb8[kk * 256 + lane],       __ATOMIC_RELAXED, __HIP_MEMORY_SCOPE_AGENT);
        a0.u[1] = __hip_atomic_load(&hb8[kk * 256 + 64 + lane],  __ATOMIC_RELAXED, __HIP_MEMORY_SCOPE_AGENT);
        a1.u[0] = __hip_atomic_load(&hb8[kk * 256 + 128 + lane], __ATOMIC_RELAXED, __HIP_MEMORY_SCOPE_AGENT);
        a1.u[1] = __hip_atomic_load(&hb8[kk * 256 + 192 + lane], __ATOMIC_RELAXED, __HIP_MEMORY_SCOPE_AGENT);
        bf16x8 b0 = *(const bf16x8*)&Bl[(0 * 16 + cn) * 520 + kk * 32 + quad * 8];
        bf16x8 b1 = *(const bf16x8*)&Bl[(1 * 16 + cn) * 520 + kk * 32 + quad * 8];
        acc[0][0] = mfma16(a0.v, b0, acc[0][0]);
        acc[0][1] = mfma16(a0.v, b1, acc[0][1]);
        acc[1][0] = mfma16(a1.v, b0, acc[1][0]);
        acc[1][1] = mfma16(a1.v, b1, acc[1][1]);
      }
    }
#pragma unroll
    for (int mt = 0; mt < 2; ++mt) {
#pragma unroll
      for (int r = 0; r < 4; ++r) {
        float ip = acc[mt][0][r], gp = acc[mt][1][r];
        float fp = __shfl(ip, lane + 8);   // f-gate partial lives 8 lanes over
        float op = __shfl(gp, lane + 8);   // o-gate partial lives 8 lanes over
        if (active) {
          float xi = ip + (float)gp_[mt][r][0];
          float xf = fp + (float)gp_[mt][r][1];
          float xg = gp + (float)gp_[mt][r][2];
          float xo = op + (float)gp_[mt][r][3];
          float it = sigmoidf_(xi);
          float ft = sigmoidf_(xf);
          float gt = tanhf_(xg);
          float ot = sigmoidf_(xo);
          float cc = ft * cst[mt][r] + it * gt;
          cst[mt][r] = cc;
          int b = mt * 16 + quad * 4 + r;
          hS[b][jj] = (bf16)(ot * tanhf_(cc));
        }
      }
    }
    __syncthreads();   // 1-wave barrier: order LDS transpose write->read
    u64 pv = *(const u64*)&hS[pb][half * 4];
    __hip_atomic_store(&hxd[(size_t)t * 4096 + sIdx], pv, __ATOMIC_RELAXED,
                       __HIP_MEMORY_SCOPE_AGENT);                 // coherent exchange
    *(u64*)&hbuf[(size_t)(t * BB) * KDIM + hbOff] = pv;           // cached, for next kernel
    asm volatile("s_waitcnt vmcnt(0)" ::: "memory");  // release: h visible before flag
    if (lane == 0)
      __hip_atomic_store(&fl[(size_t)s * 64 + wg], 1u, __ATOMIC_RELAXED,
                         __HIP_MEMORY_SCOPE_AGENT);
  }
}

// ---------------- FC: logits[b][t][c] = h1 @ fcw^T + fcb ----------------
__global__ __launch_bounds__(64) void gemm_fc_k(
    const bf16* __restrict__ hbuf,
    const bf16* __restrict__ fcw,
    const float* __restrict__ fcb,
    float* __restrict__ outp) {
  int m0 = blockIdx.x * 16;
  int lane = threadIdx.x;
  int cn = lane & 15, quad = lane >> 4;
  f32x4 acc0 = {0.f, 0.f, 0.f, 0.f}, acc1 = {0.f, 0.f, 0.f, 0.f};
  for (int k0 = 0; k0 < KDIM; k0 += 32) {
    bf16x8 a  = *(const bf16x8*)&hbuf[(size_t)(m0 + cn) * KDIM + k0 + quad * 8];
    bf16x8 b0 = *(const bf16x8*)&fcw[(size_t)cn * KDIM + k0 + quad * 8];
    bf16x8 b1 = *(const bf16x8*)&fcw[(size_t)(cn + 16) * KDIM + k0 + quad * 8];
    acc0 = mfma16(a, b0, acc0);
    acc1 = mfma16(a, b1, acc1);
  }
#pragma unroll
  for (int r = 0; r < 4; ++r) {
    int row = m0 + quad * 4 + r;
    int t = row >> 5, b = row & 31;
    float* o = outp + (size_t)b * (TT * CC_) + (size_t)t * CC_;
    o[cn] = acc0[r] + fcb[cn];
    int c1 = cn + 16;
    if (c1 < CC_) o[c1] = acc1[r] + fcb[c1];
  }
  if (blockIdx.x == 0 && lane == 0) outp[(size_t)BB * TT * CC_] = 0.f;
}

// ---------------- CRF: one WG per batch element ----------------
__global__ __launch_bounds__(64) void crf_k(
    const float* __restrict__ em,
    const int* __restrict__ labels,
    const float* __restrict__ start_, const float* __restrict__ end_,
    const float* __restrict__ trans, float* __restrict__ result) {
  int b = blockIdx.x;
  int j = threadIdx.x;
  bool act = j < CC_;
  int jc = act ? j : 0;
  float tcol[CC_];
#pragma unroll
  for (int i = 0; i < CC_; ++i) tcol[i] = trans[i * CC_ + jc];
  const float* emb_ = em + (size_t)b * (TT * CC_);
  float alpha = act ? (start_[jc] + emb_[jc]) : -1e30f;
  for (int t = 1; t < TT; ++t) {
    float m = -1e30f;
#pragma unroll
    for (int i = 0; i < CC_; ++i) {
      float ai = __shfl(alpha, i);
      m = fmaxf(m, ai + tcol[i]);
    }
    float ssum = 0.f;
#pragma unroll
    for (int i = 0; i < CC_; ++i) {
      float ai = __shfl(alpha, i);
      ssum += __expf(ai + tcol[i] - m);
    }
    float na = m + __logf(ssum) + emb_[(size_t)t * CC_ + jc];
    alpha = act ? na : -1e30f;
  }
  float v = act ? (alpha + end_[jc]) : -1e30f;
  float mm = v;
#pragma unroll
  for (int off = 32; off; off >>= 1) mm = fmaxf(mm, __shfl_xor(mm, off));
  float e = act ? __expf(v - mm) : 0.f;
#pragma unroll
  for (int off = 32; off; off >>= 1) e += __shfl_xor(e, off);
  float logZ = mm + __logf(e);
  float part = 0.f;
  for (int t = j; t < TT; t += 64) {
    int tag = labels[b * TT + t];
    part += emb_[(size_t)t * CC_ + tag];
    if (t < TT - 1) part += trans[tag * CC_ + labels[b * TT + t + 1]];
  }
#pragma unroll
  for (int off = 32; off; off >>= 1) part += __shfl_xor(part, off);
  if (j == 0) {
    float num = part + start_[labels[b * TT]] + end_[labels[b * TT + TT - 1]];
    atomicAdd(result, logZ - num);
  }
}

extern "C" void kernel_launch(void* const* d_in, const int* in_sizes, int n_in,
                              void* d_out, int out_size, void* d_ws, size_t ws_size,
                              hipStream_t stream) {
  const int*   x      = (const int*)d_in[0];
  const int*   labels = (const int*)d_in[1];
  const float* emb    = (const float*)d_in[2];
  const float* w_ih   = (const float*)d_in[3];
  const float* w_hh   = (const float*)d_in[4];
  const float* b_ih   = (const float*)d_in[5];
  const float* b_hh   = (const float*)d_in[6];
  const float* fc_w   = (const float*)d_in[7];
  const float* fc_b   = (const float*)d_in[8];
  const float* crf_s  = (const float*)d_in[9];
  const float* crf_e  = (const float*)d_in[10];
  const float* crf_t  = (const float*)d_in[11];
  float* out = (float*)d_out;
  (void)in_sizes; (void)n_in; (void)out_size; (void)ws_size;

  // workspace carve-up (~294 MB)
  char* ws = (char*)d_ws;
  bf16* xt    = (bf16*)ws;                         //  33,554,432 B
  bf16* h0    = (bf16*)(ws + 33554432);            //  33,554,432
  bf16* h1    = (bf16*)(ws + 67108864);            //  33,554,432
  bf16* wihb  = (bf16*)(ws + 100663296);           //  16,777,216
  bf16* whhb  = (bf16*)(ws + 117440512);           //   8,388,608
  bf16* fcwb  = (bf16*)(ws + 125829120);           //      65,536
  f16*  gin   = (f16*)(ws + 125894656);            // 134,217,728 (fp16)
  u64*  hx    = (u64*)(ws + 260112384);            //  33,554,432
  u32*  flags = (u32*)(ws + 293666816);            //     524,288

  hipMemsetAsync(flags, 0, 2 * 2 * TT * 64 * sizeof(u32), stream);
  convert_w_k<<<2048, 256, 0, stream>>>(w_ih, w_hh, fc_w, wihb, whhb, fcwb);
  embed_k<<<MROWS, 64, 0, stream>>>(x, emb, xt);

  // layer 0
  gemm_in_k<<<dim3(16, 128, 2), 256, 0, stream>>>(xt, wihb, b_ih, b_hh, gin);
  rec_k<<<dim3(64, 2), 64, 0, stream>>>(gin, whhb, h0, hx, flags);
  // layer 1
  gemm_in_k<<<dim3(16, 128, 2), 256, 0, stream>>>(
      h0, wihb + (size_t)2 * NGATE * KDIM, b_ih + 2 * NGATE, b_hh + 2 * NGATE, gin);
  rec_k<<<dim3(64, 2), 64, 0, stream>>>(
      gin, whhb + (size_t)2 * NGATE * HH, h1, hx, flags + 2 * TT * 64);

  gemm_fc_k<<<MROWS / 16, 64, 0, stream>>>(h1, fcwb, fc_b, out);
  crf_k<<<BB, 64, 0, stream>>>(out, labels, crf_s, crf_e, crf_t,
                               out + (size_t)BB * TT * CC_);
}